// Round 3
// baseline (57169.421 us; speedup 1.0000x reference)
//
#include <hip/hip_runtime.h>
#include <math.h>

// ---------------------------------------------------------------------------
// 2-layer bidirectional LSTM, variational dropout, fp32 — PERSISTENT kernels.
// 3 launches total: init_ws, lstm_layer<0>, lstm_layer<1>.
// Each layer kernel: 256 WGs (1/CU, co-resident) x 256 thr, 512 internal
// timesteps separated by a custom device-scope grid barrier (2-level:
// 32 leaves x 8 -> root -> generation; agent-scope atomics + __threadfence).
// Per step: gates = [x_t*mx, h*mh] @ W_cat^T + b via LDS-tiled fp32 GEMM,
// 4x4 register tile/lane, double-buffered chunks, prefetch-after-barrier.
// ---------------------------------------------------------------------------

#define SLEN   512
#define HID    512
#define CHK    64
#define APAD   68                         // padded LDS row stride (floats)
#define OUT_SEQ  (SLEN*64*2*HID)          // 33,554,432 floats
#define STATE_SZ (4*64*HID)               // 131,072 floats

__global__ __launch_bounds__(256) void init_ws(float* __restrict__ hmT,
                                               unsigned* __restrict__ bar) {
    const int b = blockIdx.x, t = threadIdx.x;
    if (b < 128) {
        *(float4*)(hmT + (b*256 + t)*4) = make_float4(0.f, 0.f, 0.f, 0.f);
    } else {
        bar[(b - 128)*256 + t] = 0u;      // 8 WGs x 256 = 2048 u32
    }
}

// two-level grid barrier: WG g arrives at leaf (g&31); 8/leaf -> root(32) ->
// gen bump.  bar layout (u32): leaf[l] at l*16 (0..511), root at 512, gen 513.
__device__ __forceinline__ void grid_bar(unsigned* bar, unsigned my, int g) {
    __syncthreads();                       // all WG stores reach L2 (vmcnt(0))
    if (threadIdx.x == 0) {
        __threadfence();                   // release: wb dirty L2 to coherence pt
        unsigned lo = __hip_atomic_fetch_add(bar + (g & 31)*16, 1u,
                          __ATOMIC_RELAXED, __HIP_MEMORY_SCOPE_AGENT);
        if (lo == 7u) {
            unsigned ro = __hip_atomic_fetch_add(bar + 512, 1u,
                              __ATOMIC_RELAXED, __HIP_MEMORY_SCOPE_AGENT);
            if (ro == 31u) {               // last WG of the whole grid
                for (int i = 0; i < 32; ++i)
                    __hip_atomic_store(bar + i*16, 0u,
                        __ATOMIC_RELAXED, __HIP_MEMORY_SCOPE_AGENT);
                __hip_atomic_store(bar + 512, 0u,
                    __ATOMIC_RELAXED, __HIP_MEMORY_SCOPE_AGENT);
                __hip_atomic_fetch_add(bar + 513, 1u,
                    __ATOMIC_RELEASE, __HIP_MEMORY_SCOPE_AGENT);
            }
        }
        while (__hip_atomic_load(bar + 513, __ATOMIC_RELAXED,
                                 __HIP_MEMORY_SCOPE_AGENT) <= my)
            __builtin_amdgcn_s_sleep(1);
        __threadfence();                   // acquire: inv L1/L2 before reads
    }
    __syncthreads();
}

template<int LAYER>
__global__ __launch_bounds__(256) void lstm_layer(
    const float* __restrict__ x,      // [512,64,512]
    const float* __restrict__ Wih0,   // [2,2048,512]
    const float* __restrict__ Wih1,   // [2,2048,1024]
    const float* __restrict__ Whh,    // [4,2048,512]
    const float* __restrict__ bih,    // [4,2048]
    const float* __restrict__ bhh,    // [4,2048]
    const float* __restrict__ mx0,    // [2,64,512]
    const float* __restrict__ mx1,    // [2,64,1024]
    const float* __restrict__ mhm,    // [4,64,512]
    float* __restrict__ out0,         // ws: [512,64,1024] layer-0 output
    float* __restrict__ hmT,          // ws: [4,512,64]  (h*mh)^T
    float* __restrict__ cst,          // ws: [4,64,512]  cell state
    unsigned* __restrict__ barbase,   // ws: barrier blocks
    float* __restrict__ dout)         // [S,B,1024] ++ hn[4,64,512] ++ cn[4,64,512]
{
    constexpr int Kin = LAYER ? 1024 : 512;
    constexpr int NCH = (Kin + HID)/CHK;       // 16 (L0) or 24 (L1)

    __shared__ __align__(16) float At[2][CHK*APAD];   // 2 x 17.4 KB
    __shared__ __align__(16) float Wt[2][CHK*16];     // 2 x 4 KB

    unsigned* bar  = barbase + LAYER*1024;

    const int g    = blockIdx.x;
    const int dir  = g >> 7;
    const int wg   = g & 127;
    const int cell = LAYER*2 + dir;
    const int u0   = wg*4;
    const int tid  = threadIdx.x;
    const int lane = tid & 63;
    const int wv   = tid >> 6;

    const int r0 = (lane & 15)*4;              // batch rows (compute tile)
    const int c0 = (lane >> 4)*4;              // local gate cols

    const int sb = tid >> 2;                   // A x-part: batch row
    const int ak = (tid & 3)*4;                // A x-part: k sub-offset
    const int hr = tid >> 4;                   // A h-part: row
    const int hb = (tid & 15)*4;               // A h-part: b offset
    const int wc   = tid >> 4;                 // W: logical col
    const int wko  = (tid & 15)*4;             // W: k block of 4
    const int wkey = ((tid & 15) >> 1) & 3;
    const int wpc  = (((wc >> 2) ^ wkey) << 2) | (wc & 3);   // physical col
    const int gcw  = (wc >> 2)*512 + u0 + (wc & 3);          // global gate row

    const int pbA = (((c0 >> 2) ^ ((wv*2    ) & 3)) << 2);
    const int pbB = (((c0 >> 2) ^ ((wv*2 + 1) & 3)) << 2);

    const int eb = tid & 63;                   // elementwise: batch
    const int eu = tid >> 6;                   // elementwise: unit
    const size_t sidx = ((size_t)(cell*64 + eb))*512 + u0 + eu;
    const float bsum[4] = {
        bih[cell*2048 + 0*512 + u0 + eu] + bhh[cell*2048 + 0*512 + u0 + eu],
        bih[cell*2048 + 1*512 + u0 + eu] + bhh[cell*2048 + 1*512 + u0 + eu],
        bih[cell*2048 + 2*512 + u0 + eu] + bhh[cell*2048 + 2*512 + u0 + eu],
        bih[cell*2048 + 3*512 + u0 + eu] + bhh[cell*2048 + 3*512 + u0 + eu] };

    for (int s = 0; s < SLEN; ++s) {
        const int t = dir ? (SLEN-1-s) : s;

        float acc[4][4];
#pragma unroll
        for (int i = 0; i < 4; ++i)
#pragma unroll
            for (int j = 0; j < 4; ++j) acc[i][j] = 0.0f;

        float4 va0, va1, va2, va3, vm0, vm1, vm2, vm3, w4;
        bool xpart = true;

        auto prefetch = [&](int ch) {
            const int k0 = ch*CHK;
            xpart = (k0 < Kin);
            if (xpart) {
                const float *asrc, *amsk, *wsrc;
                if (LAYER == 0) {
                    asrc = x   + ((size_t)(t*64   + sb))*512  + k0 + ak;
                    amsk = mx0 + ((size_t)(dir*64 + sb))*512  + k0 + ak;
                    wsrc = Wih0 + (size_t)dir*2048*512  + (size_t)gcw*512  + k0 + wko;
                } else {
                    asrc = out0 + ((size_t)(t*64   + sb))*1024 + k0 + ak;
                    amsk = mx1  + ((size_t)(dir*64 + sb))*1024 + k0 + ak;
                    wsrc = Wih1 + (size_t)dir*2048*1024 + (size_t)gcw*1024 + k0 + wko;
                }
                va0 = *(const float4*)(asrc);      vm0 = *(const float4*)(amsk);
                va1 = *(const float4*)(asrc + 16); vm1 = *(const float4*)(amsk + 16);
                va2 = *(const float4*)(asrc + 32); vm2 = *(const float4*)(amsk + 32);
                va3 = *(const float4*)(asrc + 48); vm3 = *(const float4*)(amsk + 48);
                w4  = *(const float4*)(wsrc);
            } else {
                const int kh = k0 - Kin;
                const float* hsrc = hmT + ((size_t)(cell*512 + kh + hr))*64 + hb;
                va0 = *(const float4*)(hsrc);
                va1 = *(const float4*)(hsrc + 16*64);
                va2 = *(const float4*)(hsrc + 32*64);
                va3 = *(const float4*)(hsrc + 48*64);
                w4  = *(const float4*)(Whh + (size_t)cell*2048*512
                                           + (size_t)gcw*512 + kh + wko);
            }
        };

        auto writeb = [&](float* Ab, float* Wb) {
            if (xpart) {
#define WRQ(Q, V, M)  { \
                Ab[(ak + (Q)*16 + 0)*APAD + sb] = V.x*M.x; \
                Ab[(ak + (Q)*16 + 1)*APAD + sb] = V.y*M.y; \
                Ab[(ak + (Q)*16 + 2)*APAD + sb] = V.z*M.z; \
                Ab[(ak + (Q)*16 + 3)*APAD + sb] = V.w*M.w; }
                WRQ(0, va0, vm0) WRQ(1, va1, vm1) WRQ(2, va2, vm2) WRQ(3, va3, vm3)
#undef WRQ
            } else {
                *(float4*)(Ab + (hr +  0)*APAD + hb) = va0;
                *(float4*)(Ab + (hr + 16)*APAD + hb) = va1;
                *(float4*)(Ab + (hr + 32)*APAD + hb) = va2;
                *(float4*)(Ab + (hr + 48)*APAD + hb) = va3;
            }
            Wb[(wko+0)*16 + wpc] = w4.x;
            Wb[(wko+1)*16 + wpc] = w4.y;
            Wb[(wko+2)*16 + wpc] = w4.z;
            Wb[(wko+3)*16 + wpc] = w4.w;
        };

        auto compute = [&](const float* Ab, const float* Wb) {
#pragma unroll
            for (int kk = 0; kk < 16; ++kk) {
                const int krow = wv*16 + kk;
                const float4 a = *(const float4*)(Ab + krow*APAD + r0);
                const float4 w = *(const float4*)(Wb + krow*16 + (kk < 8 ? pbA : pbB));
                acc[0][0] += a.x*w.x; acc[0][1] += a.x*w.y; acc[0][2] += a.x*w.z; acc[0][3] += a.x*w.w;
                acc[1][0] += a.y*w.x; acc[1][1] += a.y*w.y; acc[1][2] += a.y*w.z; acc[1][3] += a.y*w.w;
                acc[2][0] += a.z*w.x; acc[2][1] += a.z*w.y; acc[2][2] += a.z*w.z; acc[2][3] += a.z*w.w;
                acc[3][0] += a.w*w.x; acc[3][1] += a.w*w.y; acc[3][2] += a.w*w.z; acc[3][3] += a.w*w.w;
            }
        };

        // ---- pipelined K loop ----
        prefetch(0);
        writeb(At[0], Wt[0]);
        for (int ch = 0; ch < NCH; ++ch) {
            __syncthreads();
            const int p = ch & 1;
            if (ch + 1 < NCH) prefetch(ch + 1);
            compute(At[p], Wt[p]);
            if (ch + 1 < NCH) writeb(At[p^1], Wt[p^1]);
        }

        // ---- cross-wave reduce in At[0] ----
        float* red = At[0];
#pragma unroll
        for (int j = 0; j < 4; ++j)
            *(float4*)(red + wv*1024 + (c0+j)*64 + r0) =
                make_float4(acc[0][j], acc[1][j], acc[2][j], acc[3][j]);
        __syncthreads();

        // ---- elementwise + state update ----
        {
            float gq[4];
#pragma unroll
            for (int q = 0; q < 4; ++q) {
                const int c = q*4 + eu;
                gq[q] = red[c*64 + eb] + red[1024 + c*64 + eb]
                      + red[2048 + c*64 + eb] + red[3072 + c*64 + eb] + bsum[q];
            }
            const float cprev = (s > 0) ? cst[sidx] : 0.0f;
            const float ig = 1.0f/(1.0f + expf(-gq[0]));
            const float fg = 1.0f/(1.0f + expf(-gq[1]));
            const float gg = tanhf(gq[2]);
            const float og = 1.0f/(1.0f + expf(-gq[3]));
            const float cnew = fg*cprev + ig*gg;
            const float hnew = og*tanhf(cnew);
            cst[sidx] = cnew;
            hmT[((size_t)(cell*512 + u0 + eu))*64 + eb] = hnew * mhm[sidx];
            float* obase = LAYER ? dout : out0;
            obase[((size_t)(t*64 + eb))*1024 + dir*512 + u0 + eu] = hnew;
            if (s == SLEN-1) {
                dout[OUT_SEQ + sidx]            = hnew;   // h_n
                dout[OUT_SEQ + STATE_SZ + sidx] = cnew;   // c_n
            }
        }

        if (s + 1 < SLEN) grid_bar(bar, (unsigned)s, g);
    }
}

extern "C" void kernel_launch(void* const* d_in, const int* in_sizes, int n_in,
                              void* d_out, int out_size, void* d_ws, size_t ws_size,
                              hipStream_t stream)
{
    const float* x    = (const float*)d_in[0];
    const float* Wih0 = (const float*)d_in[1];
    const float* Wih1 = (const float*)d_in[2];
    const float* Whh  = (const float*)d_in[3];
    const float* bih  = (const float*)d_in[4];
    const float* bhh  = (const float*)d_in[5];
    const float* mx0  = (const float*)d_in[6];
    const float* mx1  = (const float*)d_in[7];
    const float* mhm  = (const float*)d_in[8];

    float* out  = (float*)d_out;
    float* out0 = (float*)d_ws;                    // [512,64,1024]
    float* hmT  = out0 + OUT_SEQ;                  // [4,512,64]
    float* cst  = hmT + STATE_SZ;                  // [4,64,512]
    unsigned* bar = (unsigned*)(cst + STATE_SZ);   // 2 x 1024 u32

    init_ws<<<136, 256, 0, stream>>>(hmT, bar);
    lstm_layer<0><<<256, 256, 0, stream>>>(x, Wih0, Wih1, Whh, bih, bhh,
                                           mx0, mx1, mhm, out0, hmT, cst, bar, out);
    lstm_layer<1><<<256, 256, 0, stream>>>(x, Wih0, Wih1, Whh, bih, bhh,
                                           mx0, mx1, mhm, out0, hmT, cst, bar, out);
}

// Round 5
// 29071.423 us; speedup vs baseline: 1.9665x; 1.9665x over previous
//
#include <hip/hip_runtime.h>
#include <math.h>

// ---------------------------------------------------------------------------
// 2-layer bidirectional LSTM, variational dropout, fp32 — persistent kernels.
// Round 5 = round 4 (fence-free barrier + sc0sc1 h-path) hardened:
//   * hmT double-buffered by step parity -> closes the WAR race where a fast
//     WG overwrites h(s) slices before a slow same-cell WG has read them.
//   * split-phase barrier: arrive after h-store (non-blocking), wait only
//     just before the first h-chunk prefetch -> barrier latency hidden under
//     x-part compute (~1.5us L0 / ~3.2us L1).
//   * asm operands use ext_vector f32x4 (HIP float4 is a struct; unsafe in
//     "=v" constraints).
// Coherence: h goes through the fabric point (sc0 sc1 stores write-through,
// sc0 sc1 loads bypass stale L1/L2); barrier = relaxed agent-scope atomics,
// NO threadfence (round 3: __threadfence wiped L2 -> 9.5 MB/step weight
// re-fetch -> 65 us/step). Weights/x/masks stay L2-resident.
// ---------------------------------------------------------------------------

typedef float f32x4 __attribute__((ext_vector_type(4)));

#define SLEN   512
#define HID    512
#define CHK    64
#define APAD   68                         // padded LDS row stride (floats)
#define OUT_SEQ  (SLEN*64*2*HID)          // 33,554,432 floats
#define STATE_SZ (4*64*HID)               // 131,072 floats (one h buffer)

__global__ __launch_bounds__(256) void init_ws(float* __restrict__ hmT,
                                               unsigned* __restrict__ bar) {
    const int b = blockIdx.x, t = threadIdx.x;
    if (b < 128) {                         // zero h buffer 0 (h0 = 0)
        *(f32x4*)(hmT + (b*256 + t)*4) = (f32x4){0.f, 0.f, 0.f, 0.f};
    } else {                               // zero barrier block (2048 u32)
        bar[(b - 128)*256 + t] = 0u;
    }
}

// bar layout (u32): leaf[l] at l*16 (l=0..31), root at 512, gen at 513.
// All relaxed agent-scope (fabric RMW, cross-XCD coherent — proven round 3).
__device__ __forceinline__ void bar_arrive(unsigned* bar, int g) {
    __syncthreads();                  // drain all waves' h-stores (vmcnt(0))
    if (threadIdx.x == 0) {
        unsigned lo = __hip_atomic_fetch_add(bar + (g & 31)*16, 1u,
                          __ATOMIC_RELAXED, __HIP_MEMORY_SCOPE_AGENT);
        if (lo == 7u) {
            unsigned ro = __hip_atomic_fetch_add(bar + 512, 1u,
                              __ATOMIC_RELAXED, __HIP_MEMORY_SCOPE_AGENT);
            if (ro == 31u) {          // last WG grid-wide: reset, then bump gen
                for (int i = 0; i < 32; ++i)
                    __hip_atomic_store(bar + i*16, 0u,
                        __ATOMIC_RELAXED, __HIP_MEMORY_SCOPE_AGENT);
                __hip_atomic_store(bar + 512, 0u,
                    __ATOMIC_RELAXED, __HIP_MEMORY_SCOPE_AGENT);
                asm volatile("s_waitcnt vmcnt(0)" ::: "memory"); // resets first
                __hip_atomic_fetch_add(bar + 513, 1u,
                    __ATOMIC_RELAXED, __HIP_MEMORY_SCOPE_AGENT);
            }
        }
    }   // non-last WGs continue immediately (split-phase: no spin here)
}

__device__ __forceinline__ void bar_wait(unsigned* bar, unsigned s) {
    if (threadIdx.x == 0) {
        while (__hip_atomic_load(bar + 513, __ATOMIC_RELAXED,
                                 __HIP_MEMORY_SCOPE_AGENT) < s)
            __builtin_amdgcn_s_sleep(1);
    }
    __syncthreads();
}

template<int LAYER>
__global__ __launch_bounds__(256) void lstm_layer(
    const float* __restrict__ x,      // [512,64,512]
    const float* __restrict__ Wih0,   // [2,2048,512]
    const float* __restrict__ Wih1,   // [2,2048,1024]
    const float* __restrict__ Whh,    // [4,2048,512]
    const float* __restrict__ bih,    // [4,2048]
    const float* __restrict__ bhh,    // [4,2048]
    const float* __restrict__ mx0,    // [2,64,512]
    const float* __restrict__ mx1,    // [2,64,1024]
    const float* __restrict__ mhm,    // [4,64,512]
    float* __restrict__ out0,         // ws: [512,64,1024] layer-0 output
    float* __restrict__ hmT,          // ws: [2][4,512,64] (h*mh)^T, dbl-buffered
    unsigned* __restrict__ barbase,   // ws: barrier blocks
    float* __restrict__ dout)         // [S,B,1024] ++ hn[4,64,512] ++ cn[4,64,512]
{
    constexpr int Kin = LAYER ? 1024 : 512;
    constexpr int NCH = (Kin + HID)/CHK;       // 16 (L0) or 24 (L1)
    constexpr int HCH = Kin/CHK;               // first h chunk: 8 (L0) / 16 (L1)

    __shared__ __align__(16) float At[2][CHK*APAD];   // 2 x 17.4 KB
    __shared__ __align__(16) float Wt[2][CHK*16];     // 2 x 4 KB

    unsigned* bar  = barbase + LAYER*1024;

    const int g    = blockIdx.x;
    const int dir  = g >> 7;
    const int wg   = g & 127;
    const int cell = LAYER*2 + dir;
    const int u0   = wg*4;
    const int tid  = threadIdx.x;
    const int lane = tid & 63;
    const int wv   = tid >> 6;

    const int r0 = (lane & 15)*4;              // batch rows (compute tile)
    const int c0 = (lane >> 4)*4;              // local gate cols

    const int sb = tid >> 2;                   // A x-part: batch row
    const int ak = (tid & 3)*4;                // A x-part: k sub-offset
    const int hr = tid >> 4;                   // A h-part: row
    const int hb = (tid & 15)*4;               // A h-part: b offset
    const int wc   = tid >> 4;                 // W: logical col
    const int wko  = (tid & 15)*4;             // W: k block of 4
    const int wkey = ((tid & 15) >> 1) & 3;
    const int wpc  = (((wc >> 2) ^ wkey) << 2) | (wc & 3);   // physical col
    const int gcw  = (wc >> 2)*512 + u0 + (wc & 3);          // global gate row

    const int pbA = (((c0 >> 2) ^ ((wv*2    ) & 3)) << 2);
    const int pbB = (((c0 >> 2) ^ ((wv*2 + 1) & 3)) << 2);

    const int eb = tid & 63;                   // elementwise: batch
    const int eu = tid >> 6;                   // elementwise: unit
    const size_t sidx = ((size_t)(cell*64 + eb))*512 + u0 + eu;
    const float bsum[4] = {
        bih[cell*2048 + 0*512 + u0 + eu] + bhh[cell*2048 + 0*512 + u0 + eu],
        bih[cell*2048 + 1*512 + u0 + eu] + bhh[cell*2048 + 1*512 + u0 + eu],
        bih[cell*2048 + 2*512 + u0 + eu] + bhh[cell*2048 + 2*512 + u0 + eu],
        bih[cell*2048 + 3*512 + u0 + eu] + bhh[cell*2048 + 3*512 + u0 + eu] };
    const float mreg = mhm[sidx];              // loop-invariant dropout mask
    float* const haddr0 = hmT + ((size_t)(cell*512 + u0 + eu))*64 + eb;
    float creg = 0.0f;                         // cell state in a register

    for (int s = 0; s < SLEN; ++s) {
        const int t = dir ? (SLEN-1-s) : s;
        const float* hrd = hmT + (size_t)(s & 1)*STATE_SZ;      // read buf
        float* const hwr = haddr0 + (size_t)((s + 1) & 1)*STATE_SZ; // write slot

        float acc[4][4];
#pragma unroll
        for (int i = 0; i < 4; ++i)
#pragma unroll
            for (int j = 0; j < 4; ++j) acc[i][j] = 0.0f;

        f32x4 va0, va1, va2, va3, vm0, vm1, vm2, vm3, w4;
        bool xpart = true;

        auto prefetch = [&](int ch) {
            const int k0 = ch*CHK;
            xpart = (k0 < Kin);
            if (xpart) {
                const float *asrc, *amsk, *wsrc;
                if (LAYER == 0) {
                    asrc = x   + ((size_t)(t*64   + sb))*512  + k0 + ak;
                    amsk = mx0 + ((size_t)(dir*64 + sb))*512  + k0 + ak;
                    wsrc = Wih0 + (size_t)dir*2048*512  + (size_t)gcw*512  + k0 + wko;
                } else {
                    asrc = out0 + ((size_t)(t*64   + sb))*1024 + k0 + ak;
                    amsk = mx1  + ((size_t)(dir*64 + sb))*1024 + k0 + ak;
                    wsrc = Wih1 + (size_t)dir*2048*1024 + (size_t)gcw*1024 + k0 + wko;
                }
                va0 = *(const f32x4*)(asrc);      vm0 = *(const f32x4*)(amsk);
                va1 = *(const f32x4*)(asrc + 16); vm1 = *(const f32x4*)(amsk + 16);
                va2 = *(const f32x4*)(asrc + 32); vm2 = *(const f32x4*)(amsk + 32);
                va3 = *(const f32x4*)(asrc + 48); vm3 = *(const f32x4*)(amsk + 48);
                w4  = *(const f32x4*)(wsrc);
            } else {
                const int kh = k0 - Kin;
                const float* hsrc = hrd + ((size_t)(cell*512 + kh + hr))*64 + hb;
                // fabric-fresh h reads: bypass stale L1/L2 (peers wrote sc0sc1)
                asm volatile("global_load_dwordx4 %0, %1, off sc0 sc1 nt"
                             : "=v"(va0) : "v"(hsrc)         : "memory");
                asm volatile("global_load_dwordx4 %0, %1, off sc0 sc1 nt"
                             : "=v"(va1) : "v"(hsrc + 16*64) : "memory");
                asm volatile("global_load_dwordx4 %0, %1, off sc0 sc1 nt"
                             : "=v"(va2) : "v"(hsrc + 32*64) : "memory");
                asm volatile("global_load_dwordx4 %0, %1, off sc0 sc1 nt"
                             : "=v"(va3) : "v"(hsrc + 48*64) : "memory");
                w4  = *(const f32x4*)(Whh + (size_t)cell*2048*512
                                           + (size_t)gcw*512 + kh + wko);
            }
        };

        auto writeb = [&](float* Ab, float* Wb) {
            if (xpart) {
#define WRQ(Q, V, M)  { \
                Ab[(ak + (Q)*16 + 0)*APAD + sb] = V.x*M.x; \
                Ab[(ak + (Q)*16 + 1)*APAD + sb] = V.y*M.y; \
                Ab[(ak + (Q)*16 + 2)*APAD + sb] = V.z*M.z; \
                Ab[(ak + (Q)*16 + 3)*APAD + sb] = V.w*M.w; }
                WRQ(0, va0, vm0) WRQ(1, va1, vm1) WRQ(2, va2, vm2) WRQ(3, va3, vm3)
#undef WRQ
            } else {
                // asm loads aren't compiler-tracked: drain before LDS write
                asm volatile("s_waitcnt vmcnt(0)" ::: "memory");
                *(f32x4*)(Ab + (hr +  0)*APAD + hb) = va0;
                *(f32x4*)(Ab + (hr + 16)*APAD + hb) = va1;
                *(f32x4*)(Ab + (hr + 32)*APAD + hb) = va2;
                *(f32x4*)(Ab + (hr + 48)*APAD + hb) = va3;
            }
            Wb[(wko+0)*16 + wpc] = w4.x;
            Wb[(wko+1)*16 + wpc] = w4.y;
            Wb[(wko+2)*16 + wpc] = w4.z;
            Wb[(wko+3)*16 + wpc] = w4.w;
        };

        auto compute = [&](const float* Ab, const float* Wb) {
#pragma unroll
            for (int kk = 0; kk < 16; ++kk) {
                const int krow = wv*16 + kk;
                const f32x4 a = *(const f32x4*)(Ab + krow*APAD + r0);
                const f32x4 w = *(const f32x4*)(Wb + krow*16 + (kk < 8 ? pbA : pbB));
                acc[0][0] += a.x*w.x; acc[0][1] += a.x*w.y; acc[0][2] += a.x*w.z; acc[0][3] += a.x*w.w;
                acc[1][0] += a.y*w.x; acc[1][1] += a.y*w.y; acc[1][2] += a.y*w.z; acc[1][3] += a.y*w.w;
                acc[2][0] += a.z*w.x; acc[2][1] += a.z*w.y; acc[2][2] += a.z*w.z; acc[2][3] += a.z*w.w;
                acc[3][0] += a.w*w.x; acc[3][1] += a.w*w.y; acc[3][2] += a.w*w.z; acc[3][3] += a.w*w.w;
            }
        };

        // ---- pipelined K loop: sync -> [wait] -> prefetch(next) -> compute ----
        prefetch(0);
        writeb(At[0], Wt[0]);
        for (int ch = 0; ch < NCH; ++ch) {
            __syncthreads();
            if (ch == HCH - 1 && s > 0)
                bar_wait(bar, (unsigned)s);      // all h(s) stores fabric-visible
            const int p = ch & 1;
            if (ch + 1 < NCH) prefetch(ch + 1);
            compute(At[p], Wt[p]);
            if (ch + 1 < NCH) writeb(At[p^1], Wt[p^1]);
        }

        // ---- cross-wave reduce in At[0] ----
        float* red = At[0];
#pragma unroll
        for (int j = 0; j < 4; ++j) {
            f32x4 v = {acc[0][j], acc[1][j], acc[2][j], acc[3][j]};
            *(f32x4*)(red + wv*1024 + (c0+j)*64 + r0) = v;
        }
        __syncthreads();

        // ---- elementwise + state update ----
        {
            float gq[4];
#pragma unroll
            for (int q = 0; q < 4; ++q) {
                const int c = q*4 + eu;
                gq[q] = red[c*64 + eb] + red[1024 + c*64 + eb]
                      + red[2048 + c*64 + eb] + red[3072 + c*64 + eb] + bsum[q];
            }
            const float ig = 1.0f/(1.0f + expf(-gq[0]));
            const float fg = 1.0f/(1.0f + expf(-gq[1]));
            const float gg = tanhf(gq[2]);
            const float og = 1.0f/(1.0f + expf(-gq[3]));
            const float cnew = fg*creg + ig*gg;
            const float hnew = og*tanhf(cnew);
            creg = cnew;
            // h*mask -> fabric coherence point (write-through)
            const float hm = hnew * mreg;
            asm volatile("global_store_dword %0, %1, off sc0 sc1 nt"
                         :: "v"(hwr), "v"(hm) : "memory");
            float* obase = LAYER ? dout : out0;
            obase[((size_t)(t*64 + eb))*1024 + dir*512 + u0 + eu] = hnew;
            if (s == SLEN-1) {
                dout[OUT_SEQ + sidx]            = hnew;   // h_n
                dout[OUT_SEQ + STATE_SZ + sidx] = cnew;   // c_n
            }
        }

        if (s + 1 < SLEN) bar_arrive(bar, g);    // non-blocking arrival
    }
}

extern "C" void kernel_launch(void* const* d_in, const int* in_sizes, int n_in,
                              void* d_out, int out_size, void* d_ws, size_t ws_size,
                              hipStream_t stream)
{
    const float* x    = (const float*)d_in[0];
    const float* Wih0 = (const float*)d_in[1];
    const float* Wih1 = (const float*)d_in[2];
    const float* Whh  = (const float*)d_in[3];
    const float* bih  = (const float*)d_in[4];
    const float* bhh  = (const float*)d_in[5];
    const float* mx0  = (const float*)d_in[6];
    const float* mx1  = (const float*)d_in[7];
    const float* mhm  = (const float*)d_in[8];

    float* out  = (float*)d_out;
    float* out0 = (float*)d_ws;                      // [512,64,1024]
    float* hmT  = out0 + OUT_SEQ;                    // [2][4,512,64]
    unsigned* bar = (unsigned*)(hmT + 2*STATE_SZ);   // 2 x 1024 u32

    init_ws<<<136, 256, 0, stream>>>(hmT, bar);
    lstm_layer<0><<<256, 256, 0, stream>>>(x, Wih0, Wih1, Whh, bih, bhh,
                                           mx0, mx1, mhm, out0, hmT, bar, out);
    lstm_layer<1><<<256, 256, 0, stream>>>(x, Wih0, Wih1, Whh, bih, bhh,
                                           mx0, mx1, mhm, out0, hmT, bar, out);
}